// Round 1
// baseline (865.823 us; speedup 1.0000x reference)
//
#include <hip/hip_runtime.h>

#define BN_EPS 1e-5f

__device__ __forceinline__ float4 f4zero() { return make_float4(0.f, 0.f, 0.f, 0.f); }

// ---------------- graph preprocessing ----------------

__global__ __launch_bounds__(256) void k_hist(const int* __restrict__ dst,
                                              int* __restrict__ counts, int e) {
    int i = blockIdx.x * 256 + threadIdx.x;
    if (i < e) atomicAdd(&counts[dst[i]], 1);
}

__global__ __launch_bounds__(256) void k_dinv(const int* __restrict__ counts,
                                              float* __restrict__ dinv, int n) {
    int i = blockIdx.x * 256 + threadIdx.x;
    if (i < n) dinv[i] = rsqrtf((float)(counts[i] + 1));  // +1 = self loop, always > 0
}

__global__ __launch_bounds__(1024) void k_scan_block(const int* __restrict__ counts,
                                                     int* __restrict__ offs,
                                                     int* __restrict__ partials, int n) {
    __shared__ int s[1024];
    int t = threadIdx.x;
    int gid = blockIdx.x * 1024 + t;
    int v = (gid < n) ? counts[gid] : 0;
    int x = v;
    s[t] = x;
    __syncthreads();
    for (int d = 1; d < 1024; d <<= 1) {
        int y = (t >= d) ? s[t - d] : 0;
        __syncthreads();
        x += y;
        s[t] = x;
        __syncthreads();
    }
    if (gid < n) offs[gid] = x - v;               // exclusive scan within block
    if (t == 1023) partials[blockIdx.x] = x;      // block total
}

__global__ void k_scan_partials(int* __restrict__ partials, int nb) {
    if (threadIdx.x == 0 && blockIdx.x == 0) {
        int run = 0;
        for (int i = 0; i < nb; ++i) { int c = partials[i]; partials[i] = run; run += c; }
        partials[nb] = run;
    }
}

__global__ __launch_bounds__(256) void k_scan_add(int* __restrict__ offs,
                                                  const int* __restrict__ partials, int n) {
    int gid = blockIdx.x * 256 + threadIdx.x;
    if (gid < n) offs[gid] += partials[gid >> 10];
    if (gid == 0) offs[n] = partials[(n + 1023) >> 10];
}

__global__ __launch_bounds__(256) void k_place(const int* __restrict__ src,
                                               const int* __restrict__ dst,
                                               const int* __restrict__ offs,
                                               int* __restrict__ cursor,
                                               const float* __restrict__ dinv,
                                               int* __restrict__ sSrc,
                                               float* __restrict__ sNrm, int e) {
    int i = blockIdx.x * 256 + threadIdx.x;
    if (i < e) {
        int d = dst[i], s = src[i];
        int p = offs[d] + atomicAdd(&cursor[d], 1);
        sSrc[p] = s;
        sNrm[p] = dinv[s] * dinv[d];
    }
}

// ---------------- GEMM: C[n,128] = A[n,128] @ W[128,128] ----------------
// 64-row tile per block; W staged in two 64-k chunks (LDS total 64 KB -> 2 blocks/CU).
// Per thread: 8 rows x 4 contiguous cols; b128 LDS reads; FMA-dominated.

__global__ __launch_bounds__(256) void k_gemm128(const float* __restrict__ A,
                                                 const float* __restrict__ W,
                                                 float* __restrict__ C, int n) {
    __shared__ float Ws[64 * 128];   // 32 KB: one 64-row chunk of W
    __shared__ float As[64 * 128];   // 32 KB: A tile, full K=128
    int tid = threadIdx.x;
    int row0 = blockIdx.x * 64;

    {   // stage A tile (2048 float4, 8 per thread)
        const float4* Av = (const float4*)A;
        float4* Asv = (float4*)As;
#pragma unroll
        for (int i = 0; i < 8; ++i) {
            int idx = tid + 256 * i;          // 0..2047
            int r = idx >> 5;                 // row in tile
            int row = row0 + r;
            Asv[idx] = (row < n) ? Av[row * 32 + (idx & 31)] : f4zero();
        }
    }

    int cg = tid & 31;     // cols 4*cg .. 4*cg+3
    int rid = tid >> 5;    // rows rid*8 .. rid*8+7
    float4 acc[8];
#pragma unroll
    for (int r = 0; r < 8; ++r) acc[r] = f4zero();

    const float4* Asv = (const float4*)As;
    const float4* Wsv = (const float4*)Ws;
    const float4* Wv = (const float4*)W;

    for (int kh = 0; kh < 2; ++kh) {
        __syncthreads();   // As ready (kh=0) / Ws chunk free for reuse (kh=1)
        {   // stage W rows [kh*64, kh*64+64): 2048 float4
            float4* Wsw = (float4*)Ws;
#pragma unroll
            for (int i = 0; i < 8; ++i) {
                int idx = tid + 256 * i;
                Wsw[idx] = Wv[kh * 2048 + idx];
            }
        }
        __syncthreads();
#pragma unroll 4
        for (int k4 = 0; k4 < 16; ++k4) {   // local k-quad within chunk
            float4 w0 = Wsv[(4 * k4 + 0) * 32 + cg];
            float4 w1 = Wsv[(4 * k4 + 1) * 32 + cg];
            float4 w2 = Wsv[(4 * k4 + 2) * 32 + cg];
            float4 w3 = Wsv[(4 * k4 + 3) * 32 + cg];
#pragma unroll
            for (int r = 0; r < 8; ++r) {
                float4 a = Asv[(rid * 8 + r) * 32 + (kh * 16 + k4)];
                acc[r].x += a.x * w0.x; acc[r].x += a.y * w1.x; acc[r].x += a.z * w2.x; acc[r].x += a.w * w3.x;
                acc[r].y += a.x * w0.y; acc[r].y += a.y * w1.y; acc[r].y += a.z * w2.y; acc[r].y += a.w * w3.y;
                acc[r].z += a.x * w0.z; acc[r].z += a.y * w1.z; acc[r].z += a.z * w2.z; acc[r].z += a.w * w3.z;
                acc[r].w += a.x * w0.w; acc[r].w += a.y * w1.w; acc[r].w += a.z * w2.w; acc[r].w += a.w * w3.w;
            }
        }
    }

#pragma unroll
    for (int r = 0; r < 8; ++r) {
        int row = row0 + rid * 8 + r;
        if (row < n) ((float4*)C)[row * 32 + cg] = acc[r];
    }
}

// ---------------- CSR aggregation + bias + ReLU + BN ----------------
// 32 lanes per node (float4 per lane = 128 features); 8 nodes per 256-block.

__global__ __launch_bounds__(256) void k_aggregate(const float4* __restrict__ A,
                                                   const int* __restrict__ offs,
                                                   const int* __restrict__ sSrc,
                                                   const float* __restrict__ sNrm,
                                                   const float* __restrict__ dinv,
                                                   const float* __restrict__ bias,
                                                   const float* __restrict__ g,
                                                   const float* __restrict__ be,
                                                   const float* __restrict__ rm,
                                                   const float* __restrict__ rv,
                                                   float4* __restrict__ Hout, int n) {
    int lane = threadIdx.x & 31;
    int node = blockIdx.x * 8 + (threadIdx.x >> 5);
    if (node >= n) return;

    float di = dinv[node];
    float wself = di * di;
    float4 a0 = A[node * 32 + lane];
    float4 acc;
    acc.x = a0.x * wself; acc.y = a0.y * wself; acc.z = a0.z * wself; acc.w = a0.w * wself;

    int e0 = offs[node], e1 = offs[node + 1];
    for (int e = e0; e < e1; ++e) {
        int s = sSrc[e];
        float w = sNrm[e];
        float4 a = A[s * 32 + lane];
        acc.x += a.x * w; acc.y += a.y * w; acc.z += a.z * w; acc.w += a.w * w;
    }

    float4 b4  = ((const float4*)bias)[lane];
    float4 g4  = ((const float4*)g)[lane];
    float4 be4 = ((const float4*)be)[lane];
    float4 rm4 = ((const float4*)rm)[lane];
    float4 rv4 = ((const float4*)rv)[lane];

    float4 o;
    float v;
    v = fmaxf(acc.x + b4.x, 0.f); o.x = (v - rm4.x) * rsqrtf(rv4.x + BN_EPS) * g4.x + be4.x;
    v = fmaxf(acc.y + b4.y, 0.f); o.y = (v - rm4.y) * rsqrtf(rv4.y + BN_EPS) * g4.y + be4.y;
    v = fmaxf(acc.z + b4.z, 0.f); o.z = (v - rm4.z) * rsqrtf(rv4.z + BN_EPS) * g4.z + be4.z;
    v = fmaxf(acc.w + b4.w, 0.f); o.w = (v - rm4.w) * rsqrtf(rv4.w + BN_EPS) * g4.w + be4.w;

    Hout[node * 32 + lane] = o;
}

// ---------------- classifier: out[n,2] = H @ Wc + bc ----------------

__global__ __launch_bounds__(256) void k_classify(const float4* __restrict__ Hn,
                                                  const float* __restrict__ Wc,
                                                  const float* __restrict__ bc,
                                                  float* __restrict__ out, int n) {
    int lane = threadIdx.x & 31;
    int node = blockIdx.x * 8 + (threadIdx.x >> 5);
    if (node >= n) return;
    float4 h = Hn[node * 32 + lane];
    const float4* Wv = (const float4*)Wc;       // Wc row-major [128][2]
    float4 w01 = Wv[2 * lane];                  // (Wc[k0][0], Wc[k0][1], Wc[k0+1][0], Wc[k0+1][1])
    float4 w23 = Wv[2 * lane + 1];
    float p0 = h.x * w01.x + h.y * w01.z + h.z * w23.x + h.w * w23.z;
    float p1 = h.x * w01.y + h.y * w01.w + h.z * w23.y + h.w * w23.w;
#pragma unroll
    for (int d = 16; d >= 1; d >>= 1) {
        p0 += __shfl_down(p0, d, 32);
        p1 += __shfl_down(p1, d, 32);
    }
    if (lane == 0) {
        out[node * 2 + 0] = p0 + bc[0];
        out[node * 2 + 1] = p1 + bc[1];
    }
}

// ---------------- launch ----------------

extern "C" void kernel_launch(void* const* d_in, const int* in_sizes, int n_in,
                              void* d_out, int out_size, void* d_ws, size_t ws_size,
                              hipStream_t stream) {
    const float* x   = (const float*)d_in[0];
    const int*   ei  = (const int*)d_in[1];    // [2,E] int32 (JAX demotes int64)
    const float* W1  = (const float*)d_in[2];
    const float* b1  = (const float*)d_in[3];
    const float* W2  = (const float*)d_in[4];
    const float* b2  = (const float*)d_in[5];
    const float* W3  = (const float*)d_in[6];
    const float* b3  = (const float*)d_in[7];
    const float* g1  = (const float*)d_in[8];
    const float* be1 = (const float*)d_in[9];
    const float* rm1 = (const float*)d_in[10];
    const float* rv1 = (const float*)d_in[11];
    const float* g2  = (const float*)d_in[12];
    const float* be2 = (const float*)d_in[13];
    const float* rm2 = (const float*)d_in[14];
    const float* rv2 = (const float*)d_in[15];
    const float* g3  = (const float*)d_in[16];
    const float* be3 = (const float*)d_in[17];
    const float* rm3 = (const float*)d_in[18];
    const float* rv3 = (const float*)d_in[19];
    const float* Wc  = (const float*)d_in[20];
    const float* bc  = (const float*)d_in[21];
    float* out = (float*)d_out;

    int n = in_sizes[0] / 128;
    int e = in_sizes[1] / 2;
    const int* src = ei;
    const int* dst = ei + e;

    char* ws = (char*)d_ws;
    size_t off = 0;
    auto alloc = [&](size_t bytes) -> char* {
        char* p = ws + off;
        off += (bytes + 255) & ~(size_t)255;
        return p;
    };
    float* bufA   = (float*)alloc((size_t)n * 128 * 4);   // GEMM output
    float* bufH   = (float*)alloc((size_t)n * 128 * 4);   // aggregated hidden
    float* dinv   = (float*)alloc((size_t)n * 4);
    int*   counts = (int*)  alloc((size_t)n * 4);
    int*   offs   = (int*)  alloc((size_t)(n + 1) * 4);
    int*   cursor = (int*)  alloc((size_t)n * 4);
    int*   parts  = (int*)  alloc(4096);
    int*   sSrc   = (int*)  alloc((size_t)e * 4);
    float* sNrm   = (float*)alloc((size_t)e * 4);
    (void)ws_size; (void)n_in; (void)out_size;

    hipMemsetAsync(counts, 0, (size_t)n * 4, stream);
    hipMemsetAsync(cursor, 0, (size_t)n * 4, stream);

    int gE = (e + 255) / 256;
    int gN = (n + 255) / 256;
    int nb = (n + 1023) / 1024;

    k_hist<<<gE, 256, 0, stream>>>(dst, counts, e);
    k_dinv<<<gN, 256, 0, stream>>>(counts, dinv, n);
    k_scan_block<<<nb, 1024, 0, stream>>>(counts, offs, parts, n);
    k_scan_partials<<<1, 64, 0, stream>>>(parts, nb);
    k_scan_add<<<gN, 256, 0, stream>>>(offs, parts, n);
    k_place<<<gE, 256, 0, stream>>>(src, dst, offs, cursor, dinv, sSrc, sNrm, e);

    int gGemm = (n + 63) / 64;
    int gAgg  = (n + 7) / 8;

    k_gemm128<<<gGemm, 256, 0, stream>>>(x, W1, bufA, n);
    k_aggregate<<<gAgg, 256, 0, stream>>>((const float4*)bufA, offs, sSrc, sNrm, dinv,
                                          b1, g1, be1, rm1, rv1, (float4*)bufH, n);

    k_gemm128<<<gGemm, 256, 0, stream>>>(bufH, W2, bufA, n);
    k_aggregate<<<gAgg, 256, 0, stream>>>((const float4*)bufA, offs, sSrc, sNrm, dinv,
                                          b2, g2, be2, rm2, rv2, (float4*)bufH, n);

    k_gemm128<<<gGemm, 256, 0, stream>>>(bufH, W3, bufA, n);
    k_aggregate<<<gAgg, 256, 0, stream>>>((const float4*)bufA, offs, sSrc, sNrm, dinv,
                                          b3, g3, be3, rm3, rv3, (float4*)bufH, n);

    k_classify<<<gAgg, 256, 0, stream>>>((const float4*)bufH, Wc, bc, out, n);
}

// Round 2
// 795.389 us; speedup vs baseline: 1.0886x; 1.0886x over previous
//
#include <hip/hip_runtime.h>

#define BN_EPS 1e-5f

__device__ __forceinline__ float4 f4zero() { return make_float4(0.f, 0.f, 0.f, 0.f); }

// ---------------- graph preprocessing ----------------

__global__ __launch_bounds__(256) void k_hist(const int* __restrict__ dst,
                                              int* __restrict__ counts, int e) {
    int i = blockIdx.x * 256 + threadIdx.x;
    if (i < e) atomicAdd(&counts[dst[i]], 1);
}

__global__ __launch_bounds__(256) void k_dinv(const int* __restrict__ counts,
                                              float* __restrict__ dinv, int n) {
    int i = blockIdx.x * 256 + threadIdx.x;
    if (i < n) dinv[i] = rsqrtf((float)(counts[i] + 1));  // +1 = self loop, always > 0
}

__global__ __launch_bounds__(1024) void k_scan_block(const int* __restrict__ counts,
                                                     int* __restrict__ offs,
                                                     int* __restrict__ partials, int n) {
    __shared__ int s[1024];
    int t = threadIdx.x;
    int gid = blockIdx.x * 1024 + t;
    int v = (gid < n) ? counts[gid] : 0;
    int x = v;
    s[t] = x;
    __syncthreads();
    for (int d = 1; d < 1024; d <<= 1) {
        int y = (t >= d) ? s[t - d] : 0;
        __syncthreads();
        x += y;
        s[t] = x;
        __syncthreads();
    }
    if (gid < n) offs[gid] = x - v;               // exclusive scan within block
    if (t == 1023) partials[blockIdx.x] = x;      // block total
}

__global__ void k_scan_partials(int* __restrict__ partials, int nb) {
    if (threadIdx.x == 0 && blockIdx.x == 0) {
        int run = 0;
        for (int i = 0; i < nb; ++i) { int c = partials[i]; partials[i] = run; run += c; }
        partials[nb] = run;
    }
}

__global__ __launch_bounds__(256) void k_scan_add(int* __restrict__ offs,
                                                  const int* __restrict__ partials, int n) {
    int gid = blockIdx.x * 256 + threadIdx.x;
    if (gid < n) offs[gid] += partials[gid >> 10];
    if (gid == 0) offs[n] = partials[(n + 1023) >> 10];
}

// edge record: (src as int bits, norm) packed into float2 -> one dwordx2 per edge
__global__ __launch_bounds__(256) void k_place(const int* __restrict__ src,
                                               const int* __restrict__ dst,
                                               const int* __restrict__ offs,
                                               int* __restrict__ cursor,
                                               const float* __restrict__ dinv,
                                               float2* __restrict__ er, int e) {
    int i = blockIdx.x * 256 + threadIdx.x;
    if (i < e) {
        int d = dst[i], s = src[i];
        int p = offs[d] + atomicAdd(&cursor[d], 1);
        er[p] = make_float2(__int_as_float(s), dinv[s] * dinv[d]);
    }
}

// ---------------- GEMM: C[n,128] = A[n,128] @ W[128,128] ----------------

__global__ __launch_bounds__(256) void k_gemm128(const float* __restrict__ A,
                                                 const float* __restrict__ W,
                                                 float* __restrict__ C, int n) {
    __shared__ float Ws[64 * 128];   // 32 KB: one 64-row chunk of W
    __shared__ float As[64 * 128];   // 32 KB: A tile, full K=128
    int tid = threadIdx.x;
    int row0 = blockIdx.x * 64;

    {   // stage A tile (2048 float4, 8 per thread)
        const float4* Av = (const float4*)A;
        float4* Asv = (float4*)As;
#pragma unroll
        for (int i = 0; i < 8; ++i) {
            int idx = tid + 256 * i;          // 0..2047
            int r = idx >> 5;                 // row in tile
            int row = row0 + r;
            Asv[idx] = (row < n) ? Av[row * 32 + (idx & 31)] : f4zero();
        }
    }

    int cg = tid & 31;     // cols 4*cg .. 4*cg+3
    int rid = tid >> 5;    // rows rid*8 .. rid*8+7
    float4 acc[8];
#pragma unroll
    for (int r = 0; r < 8; ++r) acc[r] = f4zero();

    const float4* Asv = (const float4*)As;
    const float4* Wsv = (const float4*)Ws;
    const float4* Wv = (const float4*)W;

    for (int kh = 0; kh < 2; ++kh) {
        __syncthreads();
        {   // stage W rows [kh*64, kh*64+64): 2048 float4
            float4* Wsw = (float4*)Ws;
#pragma unroll
            for (int i = 0; i < 8; ++i) {
                int idx = tid + 256 * i;
                Wsw[idx] = Wv[kh * 2048 + idx];
            }
        }
        __syncthreads();
#pragma unroll 4
        for (int k4 = 0; k4 < 16; ++k4) {   // local k-quad within chunk
            float4 w0 = Wsv[(4 * k4 + 0) * 32 + cg];
            float4 w1 = Wsv[(4 * k4 + 1) * 32 + cg];
            float4 w2 = Wsv[(4 * k4 + 2) * 32 + cg];
            float4 w3 = Wsv[(4 * k4 + 3) * 32 + cg];
#pragma unroll
            for (int r = 0; r < 8; ++r) {
                float4 a = Asv[(rid * 8 + r) * 32 + (kh * 16 + k4)];
                acc[r].x += a.x * w0.x; acc[r].x += a.y * w1.x; acc[r].x += a.z * w2.x; acc[r].x += a.w * w3.x;
                acc[r].y += a.x * w0.y; acc[r].y += a.y * w1.y; acc[r].y += a.z * w2.y; acc[r].y += a.w * w3.y;
                acc[r].z += a.x * w0.z; acc[r].z += a.y * w1.z; acc[r].z += a.z * w2.z; acc[r].z += a.w * w3.z;
                acc[r].w += a.x * w0.w; acc[r].w += a.y * w1.w; acc[r].w += a.z * w2.w; acc[r].w += a.w * w3.w;
            }
        }
    }

#pragma unroll
    for (int r = 0; r < 8; ++r) {
        int row = row0 + rid * 8 + r;
        if (row < n) ((float4*)C)[row * 32 + cg] = acc[r];
    }
}

// ---------------- CSR aggregation + bias + ReLU + BN (+ optional classifier) ----------------
// 32 lanes per node; batch-4 edge gather for MLP. FUSE_CLS: write out[n,2] instead of Hout.

template <bool FUSE_CLS>
__global__ __launch_bounds__(256) void k_aggregate(const float4* __restrict__ A,
                                                   const int* __restrict__ offs,
                                                   const float2* __restrict__ er,
                                                   const float* __restrict__ dinv,
                                                   const float* __restrict__ bias,
                                                   const float* __restrict__ g,
                                                   const float* __restrict__ be,
                                                   const float* __restrict__ rm,
                                                   const float* __restrict__ rv,
                                                   float4* __restrict__ Hout,
                                                   const float* __restrict__ Wc,
                                                   const float* __restrict__ bc,
                                                   float* __restrict__ out, int n) {
    int lane = threadIdx.x & 31;
    int node = blockIdx.x * 8 + (threadIdx.x >> 5);
    if (node >= n) return;

    float di = dinv[node];
    float wself = di * di;
    float4 a0 = A[node * 32 + lane];
    float4 acc;
    acc.x = a0.x * wself; acc.y = a0.y * wself; acc.z = a0.z * wself; acc.w = a0.w * wself;

    int e = offs[node], e1 = offs[node + 1];
    for (; e + 4 <= e1; e += 4) {
        float2 r0 = er[e + 0];
        float2 r1 = er[e + 1];
        float2 r2 = er[e + 2];
        float2 r3 = er[e + 3];
        float4 v0 = A[__float_as_int(r0.x) * 32 + lane];
        float4 v1 = A[__float_as_int(r1.x) * 32 + lane];
        float4 v2 = A[__float_as_int(r2.x) * 32 + lane];
        float4 v3 = A[__float_as_int(r3.x) * 32 + lane];
        acc.x = fmaf(v0.x, r0.y, acc.x); acc.y = fmaf(v0.y, r0.y, acc.y);
        acc.z = fmaf(v0.z, r0.y, acc.z); acc.w = fmaf(v0.w, r0.y, acc.w);
        acc.x = fmaf(v1.x, r1.y, acc.x); acc.y = fmaf(v1.y, r1.y, acc.y);
        acc.z = fmaf(v1.z, r1.y, acc.z); acc.w = fmaf(v1.w, r1.y, acc.w);
        acc.x = fmaf(v2.x, r2.y, acc.x); acc.y = fmaf(v2.y, r2.y, acc.y);
        acc.z = fmaf(v2.z, r2.y, acc.z); acc.w = fmaf(v2.w, r2.y, acc.w);
        acc.x = fmaf(v3.x, r3.y, acc.x); acc.y = fmaf(v3.y, r3.y, acc.y);
        acc.z = fmaf(v3.z, r3.y, acc.z); acc.w = fmaf(v3.w, r3.y, acc.w);
    }
    for (; e < e1; ++e) {
        float2 r = er[e];
        float4 v = A[__float_as_int(r.x) * 32 + lane];
        acc.x = fmaf(v.x, r.y, acc.x); acc.y = fmaf(v.y, r.y, acc.y);
        acc.z = fmaf(v.z, r.y, acc.z); acc.w = fmaf(v.w, r.y, acc.w);
    }

    float4 b4  = ((const float4*)bias)[lane];
    float4 g4  = ((const float4*)g)[lane];
    float4 be4 = ((const float4*)be)[lane];
    float4 rm4 = ((const float4*)rm)[lane];
    float4 rv4 = ((const float4*)rv)[lane];

    float4 o;
    float v;
    v = fmaxf(acc.x + b4.x, 0.f); o.x = (v - rm4.x) * rsqrtf(rv4.x + BN_EPS) * g4.x + be4.x;
    v = fmaxf(acc.y + b4.y, 0.f); o.y = (v - rm4.y) * rsqrtf(rv4.y + BN_EPS) * g4.y + be4.y;
    v = fmaxf(acc.z + b4.z, 0.f); o.z = (v - rm4.z) * rsqrtf(rv4.z + BN_EPS) * g4.z + be4.z;
    v = fmaxf(acc.w + b4.w, 0.f); o.w = (v - rm4.w) * rsqrtf(rv4.w + BN_EPS) * g4.w + be4.w;

    if (!FUSE_CLS) {
        Hout[node * 32 + lane] = o;
    } else {
        const float4* Wv = (const float4*)Wc;       // Wc row-major [128][2]
        float4 w01 = Wv[2 * lane];                  // (Wc[k][0],Wc[k][1],Wc[k+1][0],Wc[k+1][1])
        float4 w23 = Wv[2 * lane + 1];
        float p0 = o.x * w01.x + o.y * w01.z + o.z * w23.x + o.w * w23.z;
        float p1 = o.x * w01.y + o.y * w01.w + o.z * w23.y + o.w * w23.w;
#pragma unroll
        for (int d = 16; d >= 1; d >>= 1) {
            p0 += __shfl_down(p0, d, 32);
            p1 += __shfl_down(p1, d, 32);
        }
        if (lane == 0) {
            out[node * 2 + 0] = p0 + bc[0];
            out[node * 2 + 1] = p1 + bc[1];
        }
    }
}

// ---------------- launch ----------------

extern "C" void kernel_launch(void* const* d_in, const int* in_sizes, int n_in,
                              void* d_out, int out_size, void* d_ws, size_t ws_size,
                              hipStream_t stream) {
    const float* x   = (const float*)d_in[0];
    const int*   ei  = (const int*)d_in[1];    // [2,E] int32 (JAX demotes int64)
    const float* W1  = (const float*)d_in[2];
    const float* b1  = (const float*)d_in[3];
    const float* W2  = (const float*)d_in[4];
    const float* b2  = (const float*)d_in[5];
    const float* W3  = (const float*)d_in[6];
    const float* b3  = (const float*)d_in[7];
    const float* g1  = (const float*)d_in[8];
    const float* be1 = (const float*)d_in[9];
    const float* rm1 = (const float*)d_in[10];
    const float* rv1 = (const float*)d_in[11];
    const float* g2  = (const float*)d_in[12];
    const float* be2 = (const float*)d_in[13];
    const float* rm2 = (const float*)d_in[14];
    const float* rv2 = (const float*)d_in[15];
    const float* g3  = (const float*)d_in[16];
    const float* be3 = (const float*)d_in[17];
    const float* rm3 = (const float*)d_in[18];
    const float* rv3 = (const float*)d_in[19];
    const float* Wc  = (const float*)d_in[20];
    const float* bc  = (const float*)d_in[21];
    float* out = (float*)d_out;

    int n = in_sizes[0] / 128;
    int e = in_sizes[1] / 2;
    const int* src = ei;
    const int* dst = ei + e;

    char* ws = (char*)d_ws;
    size_t off = 0;
    auto alloc = [&](size_t bytes) -> char* {
        char* p = ws + off;
        off += (bytes + 255) & ~(size_t)255;
        return p;
    };
    float*  bufA   = (float*)alloc((size_t)n * 128 * 4);   // GEMM output
    float*  bufH   = (float*)alloc((size_t)n * 128 * 4);   // aggregated hidden
    float*  dinv   = (float*)alloc((size_t)n * 4);
    int*    counts = (int*)  alloc((size_t)n * 4);
    int*    offs   = (int*)  alloc((size_t)(n + 1) * 4);
    int*    cursor = (int*)  alloc((size_t)n * 4);
    int*    parts  = (int*)  alloc(4096);
    float2* er     = (float2*)alloc((size_t)e * 8);
    (void)ws_size; (void)n_in; (void)out_size;

    hipMemsetAsync(counts, 0, (size_t)n * 4, stream);
    hipMemsetAsync(cursor, 0, (size_t)n * 4, stream);

    int gE = (e + 255) / 256;
    int gN = (n + 255) / 256;
    int nb = (n + 1023) / 1024;

    k_hist<<<gE, 256, 0, stream>>>(dst, counts, e);
    k_dinv<<<gN, 256, 0, stream>>>(counts, dinv, n);
    k_scan_block<<<nb, 1024, 0, stream>>>(counts, offs, parts, n);
    k_scan_partials<<<1, 64, 0, stream>>>(parts, nb);
    k_scan_add<<<gN, 256, 0, stream>>>(offs, parts, n);
    k_place<<<gE, 256, 0, stream>>>(src, dst, offs, cursor, dinv, er, e);

    int gGemm = (n + 63) / 64;
    int gAgg  = (n + 7) / 8;

    k_gemm128<<<gGemm, 256, 0, stream>>>(x, W1, bufA, n);
    k_aggregate<false><<<gAgg, 256, 0, stream>>>((const float4*)bufA, offs, er, dinv,
                                                 b1, g1, be1, rm1, rv1, (float4*)bufH,
                                                 nullptr, nullptr, nullptr, n);

    k_gemm128<<<gGemm, 256, 0, stream>>>(bufH, W2, bufA, n);
    k_aggregate<false><<<gAgg, 256, 0, stream>>>((const float4*)bufA, offs, er, dinv,
                                                 b2, g2, be2, rm2, rv2, (float4*)bufH,
                                                 nullptr, nullptr, nullptr, n);

    k_gemm128<<<gGemm, 256, 0, stream>>>(bufH, W3, bufA, n);
    k_aggregate<true><<<gAgg, 256, 0, stream>>>((const float4*)bufA, offs, er, dinv,
                                                b3, g3, be3, rm3, rv3, nullptr,
                                                Wc, bc, out, n);
}

// Round 3
// 658.779 us; speedup vs baseline: 1.3143x; 1.2074x over previous
//
#include <hip/hip_runtime.h>
#include <hip/hip_fp16.h>

#define BN_EPS 1e-5f

__device__ __forceinline__ float4 f4zero() { return make_float4(0.f, 0.f, 0.f, 0.f); }

// ---------------- graph preprocessing ----------------

__global__ __launch_bounds__(256) void k_hist(const int* __restrict__ dst,
                                              int* __restrict__ counts, int e) {
    int i = blockIdx.x * 256 + threadIdx.x;
    if (i < e) atomicAdd(&counts[dst[i]], 1);
}

__global__ __launch_bounds__(256) void k_dinv(const int* __restrict__ counts,
                                              float* __restrict__ dinv, int n) {
    int i = blockIdx.x * 256 + threadIdx.x;
    if (i < n) dinv[i] = rsqrtf((float)(counts[i] + 1));  // +1 = self loop, always > 0
}

__global__ __launch_bounds__(1024) void k_scan_block(const int* __restrict__ counts,
                                                     int* __restrict__ offs,
                                                     int* __restrict__ partials, int n) {
    __shared__ int s[1024];
    int t = threadIdx.x;
    int gid = blockIdx.x * 1024 + t;
    int v = (gid < n) ? counts[gid] : 0;
    int x = v;
    s[t] = x;
    __syncthreads();
    for (int d = 1; d < 1024; d <<= 1) {
        int y = (t >= d) ? s[t - d] : 0;
        __syncthreads();
        x += y;
        s[t] = x;
        __syncthreads();
    }
    if (gid < n) offs[gid] = x - v;               // exclusive scan within block
    if (t == 1023) partials[blockIdx.x] = x;      // block total
}

__global__ void k_scan_partials(int* __restrict__ partials, int nb) {
    if (threadIdx.x == 0 && blockIdx.x == 0) {
        int run = 0;
        for (int i = 0; i < nb; ++i) { int c = partials[i]; partials[i] = run; run += c; }
        partials[nb] = run;
    }
}

__global__ __launch_bounds__(256) void k_scan_add(int* __restrict__ offs,
                                                  const int* __restrict__ partials, int n) {
    int gid = blockIdx.x * 256 + threadIdx.x;
    if (gid < n) offs[gid] += partials[gid >> 10];
    if (gid == 0) offs[n] = partials[(n + 1023) >> 10];
}

// edge record: (src as int bits, norm) packed into float2 -> one dwordx2 per edge
__global__ __launch_bounds__(256) void k_place(const int* __restrict__ src,
                                               const int* __restrict__ dst,
                                               const int* __restrict__ offs,
                                               int* __restrict__ cursor,
                                               const float* __restrict__ dinv,
                                               float2* __restrict__ er, int e) {
    int i = blockIdx.x * 256 + threadIdx.x;
    if (i < e) {
        int d = dst[i], s = src[i];
        int p = offs[d] + atomicAdd(&cursor[d], 1);
        er[p] = make_float2(__int_as_float(s), dinv[s] * dinv[d]);
    }
}

// ---------------- GEMM: C[n,128](f16) = A[n,128](f32) @ W[128,128](f32) ----------------
// Output stored as f16 to halve the aggregate's gather bytes (the binding constraint).

__global__ __launch_bounds__(256) void k_gemm128(const float* __restrict__ A,
                                                 const float* __restrict__ W,
                                                 uint2* __restrict__ C, int n) {
    __shared__ float Ws[64 * 128];   // 32 KB: one 64-row chunk of W
    __shared__ float As[64 * 128];   // 32 KB: A tile, full K=128
    int tid = threadIdx.x;
    int row0 = blockIdx.x * 64;

    {   // stage A tile (2048 float4, 8 per thread)
        const float4* Av = (const float4*)A;
        float4* Asv = (float4*)As;
#pragma unroll
        for (int i = 0; i < 8; ++i) {
            int idx = tid + 256 * i;          // 0..2047
            int r = idx >> 5;                 // row in tile
            int row = row0 + r;
            Asv[idx] = (row < n) ? Av[row * 32 + (idx & 31)] : f4zero();
        }
    }

    int cg = tid & 31;     // cols 4*cg .. 4*cg+3
    int rid = tid >> 5;    // rows rid*8 .. rid*8+7
    float4 acc[8];
#pragma unroll
    for (int r = 0; r < 8; ++r) acc[r] = f4zero();

    const float4* Asv = (const float4*)As;
    const float4* Wsv = (const float4*)Ws;
    const float4* Wv = (const float4*)W;

    for (int kh = 0; kh < 2; ++kh) {
        __syncthreads();
        {   // stage W rows [kh*64, kh*64+64): 2048 float4
            float4* Wsw = (float4*)Ws;
#pragma unroll
            for (int i = 0; i < 8; ++i) {
                int idx = tid + 256 * i;
                Wsw[idx] = Wv[kh * 2048 + idx];
            }
        }
        __syncthreads();
#pragma unroll 4
        for (int k4 = 0; k4 < 16; ++k4) {   // local k-quad within chunk
            float4 w0 = Wsv[(4 * k4 + 0) * 32 + cg];
            float4 w1 = Wsv[(4 * k4 + 1) * 32 + cg];
            float4 w2 = Wsv[(4 * k4 + 2) * 32 + cg];
            float4 w3 = Wsv[(4 * k4 + 3) * 32 + cg];
#pragma unroll
            for (int r = 0; r < 8; ++r) {
                float4 a = Asv[(rid * 8 + r) * 32 + (kh * 16 + k4)];
                acc[r].x += a.x * w0.x; acc[r].x += a.y * w1.x; acc[r].x += a.z * w2.x; acc[r].x += a.w * w3.x;
                acc[r].y += a.x * w0.y; acc[r].y += a.y * w1.y; acc[r].y += a.z * w2.y; acc[r].y += a.w * w3.y;
                acc[r].z += a.x * w0.z; acc[r].z += a.y * w1.z; acc[r].z += a.z * w2.z; acc[r].z += a.w * w3.z;
                acc[r].w += a.x * w0.w; acc[r].w += a.y * w1.w; acc[r].w += a.z * w2.w; acc[r].w += a.w * w3.w;
            }
        }
    }

#pragma unroll
    for (int r = 0; r < 8; ++r) {
        int row = row0 + rid * 8 + r;
        if (row < n) {
            __half2 p0 = __floats2half2_rn(acc[r].x, acc[r].y);
            __half2 p1 = __floats2half2_rn(acc[r].z, acc[r].w);
            uint2 u;
            u.x = *(unsigned int*)&p0;
            u.y = *(unsigned int*)&p1;
            C[row * 32 + cg] = u;   // row = 32 x uint2 = 128 halfs = 256 B
        }
    }
}

// ---------------- CSR aggregation + bias + ReLU + BN (+ optional classifier) ----------------
// 32 lanes per node; gathers f16 rows (256 B), accumulates f32. Batch-8 edges for MLP.

__device__ __forceinline__ void acc_row(float4& acc, uint2 q, float w) {
    float2 f01 = __half22float2(*(__half2*)&q.x);
    float2 f23 = __half22float2(*(__half2*)&q.y);
    acc.x = fmaf(f01.x, w, acc.x);
    acc.y = fmaf(f01.y, w, acc.y);
    acc.z = fmaf(f23.x, w, acc.z);
    acc.w = fmaf(f23.y, w, acc.w);
}

template <bool FUSE_CLS>
__global__ __launch_bounds__(256) void k_aggregate(const uint2* __restrict__ Ah,
                                                   const int* __restrict__ offs,
                                                   const float2* __restrict__ er,
                                                   const float* __restrict__ dinv,
                                                   const float* __restrict__ bias,
                                                   const float* __restrict__ g,
                                                   const float* __restrict__ be,
                                                   const float* __restrict__ rm,
                                                   const float* __restrict__ rv,
                                                   float4* __restrict__ Hout,
                                                   const float* __restrict__ Wc,
                                                   const float* __restrict__ bc,
                                                   float* __restrict__ out, int n) {
    int lane = threadIdx.x & 31;
    int node = blockIdx.x * 8 + (threadIdx.x >> 5);
    if (node >= n) return;

    float di = dinv[node];
    float wself = di * di;
    float4 acc = f4zero();
    acc_row(acc, Ah[node * 32 + lane], wself);   // self loop

    int e = offs[node], e1 = offs[node + 1];
    for (; e + 8 <= e1; e += 8) {
        float2 r0 = er[e + 0], r1 = er[e + 1], r2 = er[e + 2], r3 = er[e + 3];
        float2 r4 = er[e + 4], r5 = er[e + 5], r6 = er[e + 6], r7 = er[e + 7];
        uint2 v0 = Ah[__float_as_int(r0.x) * 32 + lane];
        uint2 v1 = Ah[__float_as_int(r1.x) * 32 + lane];
        uint2 v2 = Ah[__float_as_int(r2.x) * 32 + lane];
        uint2 v3 = Ah[__float_as_int(r3.x) * 32 + lane];
        uint2 v4 = Ah[__float_as_int(r4.x) * 32 + lane];
        uint2 v5 = Ah[__float_as_int(r5.x) * 32 + lane];
        uint2 v6 = Ah[__float_as_int(r6.x) * 32 + lane];
        uint2 v7 = Ah[__float_as_int(r7.x) * 32 + lane];
        acc_row(acc, v0, r0.y); acc_row(acc, v1, r1.y);
        acc_row(acc, v2, r2.y); acc_row(acc, v3, r3.y);
        acc_row(acc, v4, r4.y); acc_row(acc, v5, r5.y);
        acc_row(acc, v6, r6.y); acc_row(acc, v7, r7.y);
    }
    for (; e < e1; ++e) {
        float2 r = er[e];
        uint2 v = Ah[__float_as_int(r.x) * 32 + lane];
        acc_row(acc, v, r.y);
    }

    float4 b4  = ((const float4*)bias)[lane];
    float4 g4  = ((const float4*)g)[lane];
    float4 be4 = ((const float4*)be)[lane];
    float4 rm4 = ((const float4*)rm)[lane];
    float4 rv4 = ((const float4*)rv)[lane];

    float4 o;
    float v;
    v = fmaxf(acc.x + b4.x, 0.f); o.x = (v - rm4.x) * rsqrtf(rv4.x + BN_EPS) * g4.x + be4.x;
    v = fmaxf(acc.y + b4.y, 0.f); o.y = (v - rm4.y) * rsqrtf(rv4.y + BN_EPS) * g4.y + be4.y;
    v = fmaxf(acc.z + b4.z, 0.f); o.z = (v - rm4.z) * rsqrtf(rv4.z + BN_EPS) * g4.z + be4.z;
    v = fmaxf(acc.w + b4.w, 0.f); o.w = (v - rm4.w) * rsqrtf(rv4.w + BN_EPS) * g4.w + be4.w;

    if (!FUSE_CLS) {
        Hout[node * 32 + lane] = o;
    } else {
        const float4* Wv = (const float4*)Wc;       // Wc row-major [128][2]
        float4 w01 = Wv[2 * lane];                  // (Wc[k][0],Wc[k][1],Wc[k+1][0],Wc[k+1][1])
        float4 w23 = Wv[2 * lane + 1];
        float p0 = o.x * w01.x + o.y * w01.z + o.z * w23.x + o.w * w23.z;
        float p1 = o.x * w01.y + o.y * w01.w + o.z * w23.y + o.w * w23.w;
#pragma unroll
        for (int d = 16; d >= 1; d >>= 1) {
            p0 += __shfl_down(p0, d, 32);
            p1 += __shfl_down(p1, d, 32);
        }
        if (lane == 0) {
            out[node * 2 + 0] = p0 + bc[0];
            out[node * 2 + 1] = p1 + bc[1];
        }
    }
}

// ---------------- launch ----------------

extern "C" void kernel_launch(void* const* d_in, const int* in_sizes, int n_in,
                              void* d_out, int out_size, void* d_ws, size_t ws_size,
                              hipStream_t stream) {
    const float* x   = (const float*)d_in[0];
    const int*   ei  = (const int*)d_in[1];    // [2,E] int32 (JAX demotes int64)
    const float* W1  = (const float*)d_in[2];
    const float* b1  = (const float*)d_in[3];
    const float* W2  = (const float*)d_in[4];
    const float* b2  = (const float*)d_in[5];
    const float* W3  = (const float*)d_in[6];
    const float* b3  = (const float*)d_in[7];
    const float* g1  = (const float*)d_in[8];
    const float* be1 = (const float*)d_in[9];
    const float* rm1 = (const float*)d_in[10];
    const float* rv1 = (const float*)d_in[11];
    const float* g2  = (const float*)d_in[12];
    const float* be2 = (const float*)d_in[13];
    const float* rm2 = (const float*)d_in[14];
    const float* rv2 = (const float*)d_in[15];
    const float* g3  = (const float*)d_in[16];
    const float* be3 = (const float*)d_in[17];
    const float* rm3 = (const float*)d_in[18];
    const float* rv3 = (const float*)d_in[19];
    const float* Wc  = (const float*)d_in[20];
    const float* bc  = (const float*)d_in[21];
    float* out = (float*)d_out;

    int n = in_sizes[0] / 128;
    int e = in_sizes[1] / 2;
    const int* src = ei;
    const int* dst = ei + e;

    char* ws = (char*)d_ws;
    size_t off = 0;
    auto alloc = [&](size_t bytes) -> char* {
        char* p = ws + off;
        off += (bytes + 255) & ~(size_t)255;
        return p;
    };
    uint2*  bufA   = (uint2*)alloc((size_t)n * 128 * 2);   // GEMM output, f16 [n][128]
    float*  bufH   = (float*)alloc((size_t)n * 128 * 4);   // aggregated hidden, f32
    float*  dinv   = (float*)alloc((size_t)n * 4);
    int*    counts = (int*)  alloc((size_t)n * 4);
    int*    offs   = (int*)  alloc((size_t)(n + 1) * 4);
    int*    cursor = (int*)  alloc((size_t)n * 4);
    int*    parts  = (int*)  alloc(4096);
    float2* er     = (float2*)alloc((size_t)e * 8);
    (void)ws_size; (void)n_in; (void)out_size;

    hipMemsetAsync(counts, 0, (size_t)n * 4, stream);
    hipMemsetAsync(cursor, 0, (size_t)n * 4, stream);

    int gE = (e + 255) / 256;
    int gN = (n + 255) / 256;
    int nb = (n + 1023) / 1024;

    k_hist<<<gE, 256, 0, stream>>>(dst, counts, e);
    k_dinv<<<gN, 256, 0, stream>>>(counts, dinv, n);
    k_scan_block<<<nb, 1024, 0, stream>>>(counts, offs, parts, n);
    k_scan_partials<<<1, 64, 0, stream>>>(parts, nb);
    k_scan_add<<<gN, 256, 0, stream>>>(offs, parts, n);
    k_place<<<gE, 256, 0, stream>>>(src, dst, offs, cursor, dinv, er, e);

    int gGemm = (n + 63) / 64;
    int gAgg  = (n + 7) / 8;

    k_gemm128<<<gGemm, 256, 0, stream>>>(x, W1, bufA, n);
    k_aggregate<false><<<gAgg, 256, 0, stream>>>(bufA, offs, er, dinv,
                                                 b1, g1, be1, rm1, rv1, (float4*)bufH,
                                                 nullptr, nullptr, nullptr, n);

    k_gemm128<<<gGemm, 256, 0, stream>>>(bufH, W2, bufA, n);
    k_aggregate<false><<<gAgg, 256, 0, stream>>>(bufA, offs, er, dinv,
                                                 b2, g2, be2, rm2, rv2, (float4*)bufH,
                                                 nullptr, nullptr, nullptr, n);

    k_gemm128<<<gGemm, 256, 0, stream>>>(bufH, W3, bufA, n);
    k_aggregate<true><<<gAgg, 256, 0, stream>>>(bufA, offs, er, dinv,
                                                b3, g3, be3, rm3, rv3, nullptr,
                                                Wc, bc, out, n);
}